// Round 1
// baseline (1585.737 us; speedup 1.0000x reference)
//
#include <hip/hip_runtime.h>
#include <math.h>

constexpr int NB   = 2;
constexpr int NS   = 2048;
constexpr int NHID = 1024;
constexpr int NH   = 16;
constexpr int ND   = 64;
constexpr float FSCALE = 0.125f;   // D^-0.5

// ---------------- GEMM: C = A @ W^T ----------------
// A: [M,K] row-major, W: [N,K] row-major.
// MODE 0: C[m*N+n] (plain row-major)
// MODE 1: scatter to [B,H,S,D]: m = b*NS+s, n = h*ND+d
template<int MODE>
__global__ __launch_bounds__(256)
void gemm_bt(const float* __restrict__ A, const float* __restrict__ W,
             float* __restrict__ C, int M, int N, int K) {
    constexpr int BK = 16;
    __shared__ float As[64][BK + 1];
    __shared__ float Bs[64][BK + 1];
    const int t  = threadIdx.x;
    const int m0 = blockIdx.y * 64, n0 = blockIdx.x * 64;
    const int r0 = (t >> 4) << 2, c0 = (t & 15) << 2;
    float acc[4][4] = {};
    for (int k0 = 0; k0 < K; k0 += BK) {
        #pragma unroll
        for (int i = 0; i < 4; ++i) {
            int idx = t + i * 256;
            int r = idx >> 4, c = idx & 15;
            As[r][c] = A[(size_t)(m0 + r) * K + k0 + c];
            Bs[r][c] = W[(size_t)(n0 + r) * K + k0 + c];
        }
        __syncthreads();
        #pragma unroll
        for (int kk = 0; kk < BK; ++kk) {
            float a[4], b[4];
            #pragma unroll
            for (int i = 0; i < 4; ++i) a[i] = As[r0 + i][kk];
            #pragma unroll
            for (int j = 0; j < 4; ++j) b[j] = Bs[c0 + j][kk];
            #pragma unroll
            for (int i = 0; i < 4; ++i)
                #pragma unroll
                for (int j = 0; j < 4; ++j)
                    acc[i][j] = fmaf(a[i], b[j], acc[i][j]);
        }
        __syncthreads();
    }
    #pragma unroll
    for (int i = 0; i < 4; ++i) {
        const int m = m0 + r0 + i;
        const int n = n0 + c0;
        float4 v = make_float4(acc[i][0], acc[i][1], acc[i][2], acc[i][3]);
        if (MODE == 0) {
            *(float4*)&C[(size_t)m * N + n] = v;
        } else {
            int b = m >> 11, s = m & (NS - 1);
            int h = n >> 6,  d = n & (ND - 1);
            *(float4*)&C[((size_t)(b * NH + h) * NS + s) * ND + d] = v;
        }
    }
}

// ---------------- forget gate: LF[b,h,s] = log(sigmoid(x@Wf.T + bf) + 1e-6) --------
__global__ __launch_bounds__(256)
void fgate_kernel(const float* __restrict__ X, const float* __restrict__ Wf,
                  const float* __restrict__ bf, float* __restrict__ LF) {
    const int lane = threadIdx.x & 63;
    const int m = blockIdx.x * 4 + (threadIdx.x >> 6);   // token row 0..4095
    const int b = m >> 11, s = m & (NS - 1);
    float xv[16];
    #pragma unroll
    for (int w = 0; w < 16; ++w) xv[w] = X[(size_t)m * NHID + w * 64 + lane];
    for (int h = 0; h < NH; ++h) {
        float p = 0.f;
        #pragma unroll
        for (int w = 0; w < 16; ++w)
            p = fmaf(xv[w], Wf[(size_t)h * NHID + w * 64 + lane], p);
        #pragma unroll
        for (int off = 32; off > 0; off >>= 1) p += __shfl_down(p, off);
        if (lane == 0) {
            float z = p + bf[h];
            float f = 1.f / (1.f + expf(-z));
            LF[(size_t)(b * NH + h) * NS + s] = logf(f + 1e-6f);
        }
    }
}

// ---------------- inclusive cumsum over S per (b,h) ----------------
__global__ __launch_bounds__(256)
void cumsum_kernel(const float* __restrict__ LF, float* __restrict__ CUM) {
    __shared__ float ps[256];
    const int t = threadIdx.x;
    const float* src = LF + (size_t)blockIdx.x * NS;
    float* dst       = CUM + (size_t)blockIdx.x * NS;
    float v[8];
    float tot = 0.f;
    #pragma unroll
    for (int i = 0; i < 8; ++i) { v[i] = src[t * 8 + i]; tot += v[i]; v[i] = tot; }
    ps[t] = tot;
    __syncthreads();
    for (int off = 1; off < 256; off <<= 1) {
        float add = (t >= off) ? ps[t - off] : 0.f;
        __syncthreads();
        ps[t] += add;
        __syncthreads();
    }
    float excl = ps[t] - tot;
    #pragma unroll
    for (int i = 0; i < 8; ++i) dst[t * 8 + i] = excl + v[i];
}

// ---------------- flash attention with decay bias ----------------
__global__ __launch_bounds__(256)
void attn_kernel(const float* __restrict__ Qg, const float* __restrict__ Kg,
                 const float* __restrict__ Vg, const float* __restrict__ CUM,
                 float* __restrict__ ATT) {
    __shared__ float Qs[64][65];
    __shared__ float KS[64][65];   // K tile during scores, then P tile
    __shared__ float Vs[64][65];
    __shared__ float mrow[64], lrow[64], srow[64], cum_i[64], cum_j[64];
    const int t  = threadIdx.x;
    const int bh = blockIdx.y;
    const int i0 = blockIdx.x * 64;
    const float* Qb = Qg + (size_t)bh * NS * ND;
    const float* Kb = Kg + (size_t)bh * NS * ND;
    const float* Vb = Vg + (size_t)bh * NS * ND;
    const float* cumb = CUM + (size_t)bh * NS;
    const int r0 = (t >> 4) << 2, c0 = (t & 15) << 2;

    #pragma unroll
    for (int i = 0; i < 16; ++i) {
        int idx = t + i * 256;
        int r = idx >> 6, c = idx & 63;
        Qs[r][c] = Qb[(size_t)(i0 + r) * ND + c] * FSCALE;
    }
    if (t < 64) {
        cum_i[t] = cumb[i0 + t];
        mrow[t] = -INFINITY;
        lrow[t] = 0.f;
    }
    float acc[4][4] = {};
    for (int j0 = 0; j0 <= i0; j0 += 64) {
        #pragma unroll
        for (int i = 0; i < 16; ++i) {
            int idx = t + i * 256;
            int r = idx >> 6, c = idx & 63;
            KS[r][c] = Kb[(size_t)(j0 + r) * ND + c];
            Vs[r][c] = Vb[(size_t)(j0 + r) * ND + c];
        }
        if (t < 64) cum_j[t] = cumb[j0 + t];
        __syncthreads();

        // scores: sacc = (Q*SCALE) @ K^T
        float sacc[4][4] = {};
        #pragma unroll 8
        for (int kk = 0; kk < 64; ++kk) {
            float a[4], b[4];
            #pragma unroll
            for (int i = 0; i < 4; ++i) a[i] = Qs[r0 + i][kk];
            #pragma unroll
            for (int j = 0; j < 4; ++j) b[j] = KS[c0 + j][kk];
            #pragma unroll
            for (int i = 0; i < 4; ++i)
                #pragma unroll
                for (int j = 0; j < 4; ++j)
                    sacc[i][j] = fmaf(a[i], b[j], sacc[i][j]);
        }
        __syncthreads();   // all K reads done; KS becomes the score/P buffer

        #pragma unroll
        for (int i = 0; i < 4; ++i)
            #pragma unroll
            for (int j = 0; j < 4; ++j) {
                float sv = sacc[i][j] + cum_i[r0 + i] - cum_j[c0 + j];
                if (j0 + c0 + j > i0 + r0 + i) sv = -1e30f;   // causal mask
                KS[r0 + i][c0 + j] = sv;
            }
        __syncthreads();

        // online softmax row pass (threads 0..63, one row each)
        if (t < 64) {
            float mold = mrow[t], mx = mold;
            for (int c = 0; c < 64; ++c) mx = fmaxf(mx, KS[t][c]);
            float sc = __expf(mold - mx);           // 0 when mold = -inf
            float sum = 0.f;
            for (int c = 0; c < 64; ++c) {
                float p = __expf(KS[t][c] - mx);
                KS[t][c] = p;
                sum += p;
            }
            mrow[t] = mx;
            lrow[t] = fmaf(lrow[t], sc, sum);
            srow[t] = sc;
        }
        __syncthreads();

        // rescale accumulators, then O += P @ V
        float scl[4];
        #pragma unroll
        for (int i = 0; i < 4; ++i) scl[i] = srow[r0 + i];
        #pragma unroll
        for (int i = 0; i < 4; ++i)
            #pragma unroll
            for (int j = 0; j < 4; ++j) acc[i][j] *= scl[i];
        #pragma unroll 8
        for (int jj = 0; jj < 64; ++jj) {
            float p[4], vv[4];
            #pragma unroll
            for (int i = 0; i < 4; ++i) p[i] = KS[r0 + i][jj];
            #pragma unroll
            for (int j = 0; j < 4; ++j) vv[j] = Vs[jj][c0 + j];
            #pragma unroll
            for (int i = 0; i < 4; ++i)
                #pragma unroll
                for (int j = 0; j < 4; ++j)
                    acc[i][j] = fmaf(p[i], vv[j], acc[i][j]);
        }
        __syncthreads();
    }

    const int b = bh >> 4, h = bh & 15;
    #pragma unroll
    for (int i = 0; i < 4; ++i) {
        float inv = 1.f / lrow[r0 + i];
        float4 v = make_float4(acc[i][0] * inv, acc[i][1] * inv,
                               acc[i][2] * inv, acc[i][3] * inv);
        *(float4*)&ATT[((size_t)(b * NS + i0 + r0 + i)) * NHID + h * 64 + c0] = v;
    }
}

extern "C" void kernel_launch(void* const* d_in, const int* in_sizes, int n_in,
                              void* d_out, int out_size, void* d_ws, size_t ws_size,
                              hipStream_t stream) {
    const float* x  = (const float*)d_in[0];
    const float* Wq = (const float*)d_in[1];
    const float* Wk = (const float*)d_in[2];
    const float* Wv = (const float*)d_in[3];
    const float* Wf = (const float*)d_in[4];
    const float* bf = (const float*)d_in[5];
    const float* Wo = (const float*)d_in[6];
    float* out = (float*)d_out;

    const size_t NTOK = (size_t)NB * NS;          // 4096 token rows
    float* ws  = (float*)d_ws;
    float* Q   = ws;
    float* K   = Q + NTOK * NHID;
    float* V   = K + NTOK * NHID;
    float* ATT = V + NTOK * NHID;
    float* LF  = ATT + NTOK * NHID;
    float* CUM = LF + (size_t)NB * NH * NS;

    dim3 gg(NHID / 64, NTOK / 64);
    gemm_bt<1><<<gg, 256, 0, stream>>>(x, Wq, Q, (int)NTOK, NHID, NHID);
    gemm_bt<1><<<gg, 256, 0, stream>>>(x, Wk, K, (int)NTOK, NHID, NHID);
    gemm_bt<1><<<gg, 256, 0, stream>>>(x, Wv, V, (int)NTOK, NHID, NHID);
    fgate_kernel<<<(int)NTOK / 4, 256, 0, stream>>>(x, Wf, bf, LF);
    cumsum_kernel<<<NB * NH, 256, 0, stream>>>(LF, CUM);
    attn_kernel<<<dim3(NS / 64, NB * NH), 256, 0, stream>>>(Q, K, V, CUM, ATT);
    gemm_bt<0><<<gg, 256, 0, stream>>>(ATT, Wo, out, (int)NTOK, NHID, NHID);
}

// Round 3
// 188.320 us; speedup vs baseline: 8.4204x; 8.4204x over previous
//
#include <hip/hip_runtime.h>
#include <hip/hip_bf16.h>
#include <math.h>

typedef __attribute__((ext_vector_type(8))) short bf16x8;
typedef __attribute__((ext_vector_type(4))) short s16x4;
typedef __attribute__((ext_vector_type(4))) float f32x4;
typedef __attribute__((ext_vector_type(2))) int i32x2;

constexpr int NB = 2, NS = 2048, NHID = 1024, NH = 16, ND = 64;
constexpr float FSCALE = 0.125f;   // D^-0.5

__device__ __forceinline__ short f2bf(float f) {
    union { __hip_bfloat16 h; short s; } u;
    u.h = __float2bfloat16(f);
    return u.s;
}

__device__ __forceinline__ void gload16(const void* g, void* l) {
    __builtin_amdgcn_global_load_lds(
        (const __attribute__((address_space(1))) unsigned*)g,
        (__attribute__((address_space(3))) unsigned*)l, 16, 0, 0);
}

__device__ __forceinline__ unsigned lds_addr(void* p) {
    return (unsigned)(size_t)(__attribute__((address_space(3))) void*)p;
}

// ---------------- fp32 -> bf16 casts ----------------
__global__ __launch_bounds__(256)
void cast_x_kernel(const float* __restrict__ s, short* __restrict__ d) {
    size_t i = ((size_t)blockIdx.x*256 + threadIdx.x)*8;
    float4 a = *(const float4*)(s+i);
    float4 b = *(const float4*)(s+i+4);
    bf16x8 o;
    o[0]=f2bf(a.x); o[1]=f2bf(a.y); o[2]=f2bf(a.z); o[3]=f2bf(a.w);
    o[4]=f2bf(b.x); o[5]=f2bf(b.y); o[6]=f2bf(b.z); o[7]=f2bf(b.w);
    *(bf16x8*)(d+i) = o;
}

__global__ __launch_bounds__(256)
void cast_w_kernel(const float* __restrict__ s0, const float* __restrict__ s1,
                   const float* __restrict__ s2, const float* __restrict__ s3,
                   short* __restrict__ d0, short* __restrict__ d1,
                   short* __restrict__ d2, short* __restrict__ d3) {
    const float* s; short* d;
    switch (blockIdx.y) {
        case 0:  s = s0; d = d0; break;
        case 1:  s = s1; d = d1; break;
        case 2:  s = s2; d = d2; break;
        default: s = s3; d = d3; break;
    }
    size_t i = ((size_t)blockIdx.x*256 + threadIdx.x)*8;
    float4 a = *(const float4*)(s+i);
    float4 b = *(const float4*)(s+i+4);
    bf16x8 o;
    o[0]=f2bf(a.x); o[1]=f2bf(a.y); o[2]=f2bf(a.z); o[3]=f2bf(a.w);
    o[4]=f2bf(b.x); o[5]=f2bf(b.y); o[6]=f2bf(b.z); o[7]=f2bf(b.w);
    *(bf16x8*)(d+i) = o;
}

// ---------------- bf16 MFMA GEMM: C = A @ W^T ----------------
// A:[M,K] bf16 row-major, W:[N,K] bf16 row-major.
// MODE 0: fp32 row-major out.  MODE 1: bf16 scatter to [B,H,S,D] (mult applied).
template<int FM, int FN, int MODE>
__device__ __forceinline__ void gemm_body(
    const short* __restrict__ A, const short* __restrict__ Bm,
    float* __restrict__ Cf, short* __restrict__ Cb,
    int N, int K, float mult, int bx, int by, short* As, short* Bs)
{
    constexpr int BM = FM*32, BN = FN*32;
    const int t = threadIdx.x, w = t>>6, l = t&63, g = l>>4, r = l&15;
    const int m0 = by*BM, n0 = bx*BN;
    const int wr = (w>>1)*(FM*16), wc = (w&1)*(FN*16);
    f32x4 acc[FM][FN] = {};
    for (int k0 = 0; k0 < K; k0 += 32) {
        #pragma unroll
        for (int c = 0; c < (BM*4)/256; ++c) {
            int ci = (c*4 + w)*64 + l;          // 16B chunk: 4 chunks per 32-short row
            gload16(A + (size_t)(m0 + (ci>>2))*K + k0 + (ci&3)*8, As + (c*4+w)*512);
        }
        #pragma unroll
        for (int c = 0; c < (BN*4)/256; ++c) {
            int ci = (c*4 + w)*64 + l;
            gload16(Bm + (size_t)(n0 + (ci>>2))*K + k0 + (ci&3)*8, Bs + (c*4+w)*512);
        }
        __syncthreads();
        bf16x8 af[FM], bfv[FN];
        #pragma unroll
        for (int fm = 0; fm < FM; ++fm)
            af[fm] = *(const bf16x8*)(As + (wr + fm*16 + r)*32 + g*8);
        #pragma unroll
        for (int fn = 0; fn < FN; ++fn)
            bfv[fn] = *(const bf16x8*)(Bs + (wc + fn*16 + r)*32 + g*8);
        #pragma unroll
        for (int fm = 0; fm < FM; ++fm)
            #pragma unroll
            for (int fn = 0; fn < FN; ++fn)
                acc[fm][fn] = __builtin_amdgcn_mfma_f32_16x16x32_bf16(
                    af[fm], bfv[fn], acc[fm][fn], 0, 0, 0);
        __syncthreads();
    }
    #pragma unroll
    for (int fm = 0; fm < FM; ++fm)
        #pragma unroll
        for (int fn = 0; fn < FN; ++fn)
            #pragma unroll
            for (int rr = 0; rr < 4; ++rr) {
                int m = m0 + wr + fm*16 + g*4 + rr;   // C/D: row=(l>>4)*4+reg
                int n = n0 + wc + fn*16 + r;          //      col=l&15
                float v = acc[fm][fn][rr] * mult;
                if (MODE == 0) {
                    Cf[(size_t)m*N + n] = v;
                } else {
                    int b = m >> 11, s = m & (NS-1), hh = n >> 6, d = n & (ND-1);
                    Cb[((size_t)(b*NH + hh)*NS + s)*ND + d] = f2bf(v);
                }
            }
}

__global__ __launch_bounds__(256)
void gemm_qkv_kernel(const short* __restrict__ X,
                     const short* __restrict__ Wq, const short* __restrict__ Wk,
                     const short* __restrict__ Wv,
                     short* __restrict__ Q, short* __restrict__ Kd, short* __restrict__ V)
{
    __shared__ short As[128*32], Bs[128*32];
    const short* Bm; short* Dst; float mult;
    if (blockIdx.z == 0)      { Bm = Wq; Dst = Q;  mult = FSCALE; }
    else if (blockIdx.z == 1) { Bm = Wk; Dst = Kd; mult = 1.f; }
    else                      { Bm = Wv; Dst = V;  mult = 1.f; }
    gemm_body<4,4,1>(X, Bm, nullptr, Dst, NHID, NHID, mult, blockIdx.x, blockIdx.y, As, Bs);
}

__global__ __launch_bounds__(256)
void gemm_out_kernel(const short* __restrict__ A, const short* __restrict__ Wo,
                     float* __restrict__ C)
{
    __shared__ short As[64*32], Bs[128*32];
    gemm_body<2,4,0>(A, Wo, C, nullptr, NHID, NHID, 1.f, blockIdx.x, blockIdx.y, As, Bs);
}

// ---------------- forget gate (fp32) ----------------
__global__ __launch_bounds__(256)
void fgate_kernel(const float* __restrict__ X, const float* __restrict__ Wf,
                  const float* __restrict__ bf, float* __restrict__ LF) {
    const int lane = threadIdx.x & 63;
    const int m = blockIdx.x * 4 + (threadIdx.x >> 6);
    const int b = m >> 11, s = m & (NS - 1);
    float xv[16];
    #pragma unroll
    for (int w = 0; w < 16; ++w) xv[w] = X[(size_t)m * NHID + w * 64 + lane];
    for (int h = 0; h < NH; ++h) {
        float p = 0.f;
        #pragma unroll
        for (int w = 0; w < 16; ++w)
            p = fmaf(xv[w], Wf[(size_t)h * NHID + w * 64 + lane], p);
        #pragma unroll
        for (int off = 32; off > 0; off >>= 1) p += __shfl_down(p, off);
        if (lane == 0) {
            float z = p + bf[h];
            float f = 1.f / (1.f + expf(-z));
            LF[(size_t)(b * NH + h) * NS + s] = logf(f + 1e-6f);
        }
    }
}

// ---------------- inclusive cumsum over S per (b,h) ----------------
__global__ __launch_bounds__(256)
void cumsum_kernel(const float* __restrict__ LF, float* __restrict__ CUM) {
    __shared__ float ps[256];
    const int t = threadIdx.x;
    const float* src = LF + (size_t)blockIdx.x * NS;
    float* dst       = CUM + (size_t)blockIdx.x * NS;
    float v[8];
    float tot = 0.f;
    #pragma unroll
    for (int i = 0; i < 8; ++i) { v[i] = src[t * 8 + i]; tot += v[i]; v[i] = tot; }
    ps[t] = tot;
    __syncthreads();
    for (int off = 1; off < 256; off <<= 1) {
        float add = (t >= off) ? ps[t - off] : 0.f;
        __syncthreads();
        ps[t] += add;
        __syncthreads();
    }
    float excl = ps[t] - tot;
    #pragma unroll
    for (int i = 0; i < 8; ++i) dst[t * 8 + i] = excl + v[i];
}

// ---------------- MFMA flash attention with decay bias ----------------
// Swapped QK^T: S^T = K·Q^T so each lane owns one q-row's scores (i = l&15).
__global__ __launch_bounds__(256)
void attn_mfma(const short* __restrict__ Qg, const short* __restrict__ Kg,
               const short* __restrict__ Vg, const float* __restrict__ CUM,
               short* __restrict__ ATT) {
    __shared__ short Ks[64*64];     // row-major [j][d], XOR-swizzled
    __shared__ short Vs[64*64];     // subtiled [jb][db][4][16] for tr reads
    __shared__ short Ps[4][16*64];  // per-wave P tile [i][j], XOR-swizzled
    const int t = threadIdx.x, w = t>>6, l = t&63, g = l>>4, r = l&15;
    const int bh = blockIdx.y, b = bh>>4, h = bh&15;
    const int i0 = ((int)gridDim.x - 1 - (int)blockIdx.x) * 64;  // big tiles first
    const size_t base = (size_t)bh * NS * ND;
    const float* cumb = CUM + (size_t)bh * NS;
    const int iw = i0 + w*16 + r;               // this lane's q-row
    bf16x8 qf[2];                                // Q as B-frag (pre-scaled by FSCALE)
    qf[0] = *(const bf16x8*)(Qg + base + (size_t)iw*ND + g*8);
    qf[1] = *(const bf16x8*)(Qg + base + (size_t)iw*ND + 32 + g*8);
    const float cum_i = cumb[iw];
    float mrun = -1e30f, lrun = 0.f;
    f32x4 acc[4] = {};                           // O frags, fd=0..3
    char* PsB = (char*)Ps[w];
    const char* KsB = (const char*)Ks;
    const unsigned vsb = lds_addr(Vs);

    for (int j0 = 0; j0 <= i0; j0 += 64) {
        // ---- stage K (swizzled rows) and V (subtiled) via global_load_lds ----
        #pragma unroll
        for (int c = 0; c < 2; ++c) {
            int ci = (c*4 + w)*64 + l;           // 16B chunk in 8KB tile
            int row = ci >> 3;
            int col = (ci & 7) * 8;              // shorts
            int lcol = col ^ ((row & 7) << 3);   // pre-swizzle global source
            gload16(Kg + base + (size_t)(j0+row)*ND + lcol, Ks + (c*4+w)*512);
        }
        #pragma unroll
        for (int c = 0; c < 2; ++c) {
            int ci = (c*4 + w)*64 + l;
            int st = ci >> 3, q8 = ci & 7;
            int jb = st >> 2, db = st & 3;
            int jj = q8 >> 1, dh = q8 & 1;
            gload16(Vg + base + (size_t)(j0 + jb*4 + jj)*ND + db*16 + dh*8,
                    Vs + (c*4+w)*512);
        }
        __syncthreads();

        // ---- S^T = K·Q^T: rows j, cols i ----
        f32x4 sT[4];
        #pragma unroll
        for (int fj = 0; fj < 4; ++fj) {
            int row = fj*16 + r;
            unsigned swz = (unsigned)((row & 7) << 4);
            bf16x8 k0v = *(const bf16x8*)(KsB + ((row*128 +      g*16) ^ swz));
            bf16x8 k1v = *(const bf16x8*)(KsB + ((row*128 + 64 + g*16) ^ swz));
            f32x4 z = {};
            z = __builtin_amdgcn_mfma_f32_16x16x32_bf16(k0v, qf[0], z, 0, 0, 0);
            z = __builtin_amdgcn_mfma_f32_16x16x32_bf16(k1v, qf[1], z, 0, 0, 0);
            sT[fj] = z;
        }

        // ---- bias + causal mask; lane-local online softmax for row i=r ----
        float p[16];
        const bool diag = (j0 == i0);
        #pragma unroll
        for (int fj = 0; fj < 4; ++fj) {
            f32x4 cj = *(const f32x4*)(cumb + j0 + fj*16 + g*4);
            #pragma unroll
            for (int rr = 0; rr < 4; ++rr) {
                float sv = sT[fj][rr] + cum_i - cj[rr];
                if (diag && (j0 + fj*16 + g*4 + rr > iw)) sv = -1e30f;
                p[fj*4+rr] = sv;
            }
        }
        float mx = p[0];
        #pragma unroll
        for (int q = 1; q < 16; ++q) mx = fmaxf(mx, p[q]);
        mx = fmaxf(mx, __shfl_xor(mx, 16));
        mx = fmaxf(mx, __shfl_xor(mx, 32));
        float newm = fmaxf(mrun, mx);
        float sc = __expf(mrun - newm);
        mrun = newm;
        float tsum = 0.f;
        #pragma unroll
        for (int q = 0; q < 16; ++q) { p[q] = __expf(p[q] - newm); tsum += p[q]; }
        tsum += __shfl_xor(tsum, 16);
        tsum += __shfl_xor(tsum, 32);
        lrun = lrun * sc + tsum;

        // ---- P -> LDS (bf16, swizzled) ----
        {
            unsigned swz = (unsigned)((r & 7) << 4);
            #pragma unroll
            for (int fj = 0; fj < 4; ++fj) {
                s16x4 pk;
                pk[0]=f2bf(p[fj*4+0]); pk[1]=f2bf(p[fj*4+1]);
                pk[2]=f2bf(p[fj*4+2]); pk[3]=f2bf(p[fj*4+3]);
                *(s16x4*)(PsB + ((r*128 + fj*32 + g*8) ^ swz)) = pk;
            }
        }

        // ---- rescale O accum (rows live at i_local=(l>>4)*4+reg) ----
        float scr[4];
        #pragma unroll
        for (int rr = 0; rr < 4; ++rr) scr[rr] = __shfl(sc, g*4 + rr);
        #pragma unroll
        for (int fd = 0; fd < 4; ++fd)
            #pragma unroll
            for (int rr = 0; rr < 4; ++rr) acc[fd][rr] *= scr[rr];

        // ---- PV: O += P·V ----
        bf16x8 pa[2];
        {
            unsigned swz = (unsigned)((r & 7) << 4);
            pa[0] = *(const bf16x8*)(PsB + ((r*128 +      g*16) ^ swz));
            pa[1] = *(const bf16x8*)(PsB + ((r*128 + 64 + g*16) ^ swz));
        }
        i32x2 vt[4][4];
        #pragma unroll
        for (int fd = 0; fd < 4; ++fd)
            #pragma unroll
            for (int jc = 0; jc < 2; ++jc)
                #pragma unroll
                for (int hh = 0; hh < 2; ++hh) {
                    unsigned st = (unsigned)((jc*8 + 2*g + hh)*4 + fd);
                    // per-lane addr: subtile base + (l&15)*8 bytes -> lane gets
                    // column (l&15) of the 4x16 subtile (m156/m162 semantics)
                    unsigned ad = vsb + st*128 + (unsigned)r*8;
                    asm volatile("ds_read_b64_tr_b16 %0, %1"
                                 : "=v"(vt[fd][jc*2+hh]) : "v"(ad));
                }
        asm volatile("s_waitcnt lgkmcnt(0)" ::: "memory");
        __builtin_amdgcn_sched_barrier(0);
        #pragma unroll
        for (int fd = 0; fd < 4; ++fd) {
            union { bf16x8 v; i32x2 d2[2]; } u0, u1;
            u0.d2[0] = vt[fd][0]; u0.d2[1] = vt[fd][1];
            u1.d2[0] = vt[fd][2]; u1.d2[1] = vt[fd][3];
            acc[fd] = __builtin_amdgcn_mfma_f32_16x16x32_bf16(pa[0], u0.v, acc[fd], 0, 0, 0);
            acc[fd] = __builtin_amdgcn_mfma_f32_16x16x32_bf16(pa[1], u1.v, acc[fd], 0, 0, 0);
        }
        __syncthreads();
    }

    // ---- epilogue: normalize, write [b, s, h*64+d] bf16 ----
    float linv[4];
    #pragma unroll
    for (int rr = 0; rr < 4; ++rr) linv[rr] = 1.f / __shfl(lrun, g*4 + rr);
    #pragma unroll
    for (int fd = 0; fd < 4; ++fd)
        #pragma unroll
        for (int rr = 0; rr < 4; ++rr) {
            int i = i0 + w*16 + g*4 + rr;
            ATT[((size_t)(b*NS + i))*NHID + h*ND + fd*16 + r] = f2bf(acc[fd][rr] * linv[rr]);
        }
}

extern "C" void kernel_launch(void* const* d_in, const int* in_sizes, int n_in,
                              void* d_out, int out_size, void* d_ws, size_t ws_size,
                              hipStream_t stream) {
    const float* x  = (const float*)d_in[0];
    const float* Wq = (const float*)d_in[1];
    const float* Wk = (const float*)d_in[2];
    const float* Wv = (const float*)d_in[3];
    const float* Wf = (const float*)d_in[4];
    const float* bf = (const float*)d_in[5];
    const float* Wo = (const float*)d_in[6];
    float* out = (float*)d_out;

    const size_t NTOK = (size_t)NB * NS;          // 4096
    short* xb  = (short*)d_ws;
    short* Wqb = xb  + NTOK * NHID;
    short* Wkb = Wqb + (size_t)NHID * NHID;
    short* Wvb = Wkb + (size_t)NHID * NHID;
    short* Wob = Wvb + (size_t)NHID * NHID;
    short* Qb  = Wob + (size_t)NHID * NHID;
    short* Kb  = Qb  + NTOK * NHID;
    short* Vb  = Kb  + NTOK * NHID;
    short* ATTb= Vb  + NTOK * NHID;
    float* LF  = (float*)(ATTb + NTOK * NHID);
    float* CUM = LF + (size_t)NB * NH * NS;

    cast_x_kernel<<<2048, 256, 0, stream>>>(x, xb);
    cast_w_kernel<<<dim3(512, 4), 256, 0, stream>>>(Wq, Wk, Wv, Wo, Wqb, Wkb, Wvb, Wob);
    gemm_qkv_kernel<<<dim3(8, 32, 3), 256, 0, stream>>>(xb, Wqb, Wkb, Wvb, Qb, Kb, Vb);
    fgate_kernel<<<(int)NTOK / 4, 256, 0, stream>>>(x, Wf, bf, LF);
    cumsum_kernel<<<NB * NH, 256, 0, stream>>>(LF, CUM);
    attn_mfma<<<dim3(NS / 64, NB * NH), 256, 0, stream>>>(Qb, Kb, Vb, CUM, ATTb);
    gemm_out_kernel<<<dim3(8, 64), 256, 0, stream>>>(ATTb, Wob, out);
}

// Round 4
// 152.269 us; speedup vs baseline: 10.4141x; 1.2368x over previous
//
#include <hip/hip_runtime.h>
#include <hip/hip_bf16.h>
#include <math.h>

typedef __attribute__((ext_vector_type(8))) short bf16x8;
typedef __attribute__((ext_vector_type(4))) short s16x4;
typedef __attribute__((ext_vector_type(4))) float f32x4;
typedef __attribute__((ext_vector_type(2))) int i32x2;

constexpr int NB = 2, NS = 2048, NHID = 1024, NH = 16, ND = 64;
constexpr float FSCALE = 0.125f;                 // D^-0.5
constexpr float LOG2E  = 1.44269504088896f;
constexpr int QBLK = 128, NT = NS / QBLK;        // 16 i-tiles, fold-paired

__device__ __forceinline__ short f2bf(float f) {
    union { __hip_bfloat16 h; short s; } u;
    u.h = __float2bfloat16(f);
    return u.s;
}

__device__ __forceinline__ void gload16(const void* g, void* l) {
    __builtin_amdgcn_global_load_lds(
        (const __attribute__((address_space(1))) unsigned*)g,
        (__attribute__((address_space(3))) unsigned*)l, 16, 0, 0);
}

__device__ __forceinline__ unsigned lds_addr(void* p) {
    return (unsigned)(size_t)(__attribute__((address_space(3))) void*)p;
}

// ---------------- fp32 -> bf16 casts ----------------
__global__ __launch_bounds__(256)
void cast_x_kernel(const float* __restrict__ s, short* __restrict__ d) {
    size_t i = ((size_t)blockIdx.x*256 + threadIdx.x)*8;
    float4 a = *(const float4*)(s+i);
    float4 b = *(const float4*)(s+i+4);
    bf16x8 o;
    o[0]=f2bf(a.x); o[1]=f2bf(a.y); o[2]=f2bf(a.z); o[3]=f2bf(a.w);
    o[4]=f2bf(b.x); o[5]=f2bf(b.y); o[6]=f2bf(b.z); o[7]=f2bf(b.w);
    *(bf16x8*)(d+i) = o;
}

__global__ __launch_bounds__(256)
void cast_w_kernel(const float* __restrict__ s0, const float* __restrict__ s1,
                   const float* __restrict__ s2, const float* __restrict__ s3,
                   short* __restrict__ d0, short* __restrict__ d1,
                   short* __restrict__ d2, short* __restrict__ d3) {
    const float* s; short* d;
    switch (blockIdx.y) {
        case 0:  s = s0; d = d0; break;
        case 1:  s = s1; d = d1; break;
        case 2:  s = s2; d = d2; break;
        default: s = s3; d = d3; break;
    }
    size_t i = ((size_t)blockIdx.x*256 + threadIdx.x)*8;
    float4 a = *(const float4*)(s+i);
    float4 b = *(const float4*)(s+i+4);
    bf16x8 o;
    o[0]=f2bf(a.x); o[1]=f2bf(a.y); o[2]=f2bf(a.z); o[3]=f2bf(a.w);
    o[4]=f2bf(b.x); o[5]=f2bf(b.y); o[6]=f2bf(b.z); o[7]=f2bf(b.w);
    *(bf16x8*)(d+i) = o;
}

// ---------------- bf16 MFMA GEMM: C = A @ W^T ----------------
template<int FM, int FN, int MODE>
__device__ __forceinline__ void gemm_body(
    const short* __restrict__ A, const short* __restrict__ Bm,
    float* __restrict__ Cf, short* __restrict__ Cb,
    int N, int K, float mult, int bx, int by, short* As, short* Bs)
{
    constexpr int BM = FM*32, BN = FN*32;
    const int t = threadIdx.x, w = t>>6, l = t&63, g = l>>4, r = l&15;
    const int m0 = by*BM, n0 = bx*BN;
    const int wr = (w>>1)*(FM*16), wc = (w&1)*(FN*16);
    f32x4 acc[FM][FN] = {};
    for (int k0 = 0; k0 < K; k0 += 32) {
        #pragma unroll
        for (int c = 0; c < (BM*4)/256; ++c) {
            int ci = (c*4 + w)*64 + l;
            gload16(A + (size_t)(m0 + (ci>>2))*K + k0 + (ci&3)*8, As + (c*4+w)*512);
        }
        #pragma unroll
        for (int c = 0; c < (BN*4)/256; ++c) {
            int ci = (c*4 + w)*64 + l;
            gload16(Bm + (size_t)(n0 + (ci>>2))*K + k0 + (ci&3)*8, Bs + (c*4+w)*512);
        }
        __syncthreads();
        bf16x8 af[FM], bfv[FN];
        #pragma unroll
        for (int fm = 0; fm < FM; ++fm)
            af[fm] = *(const bf16x8*)(As + (wr + fm*16 + r)*32 + g*8);
        #pragma unroll
        for (int fn = 0; fn < FN; ++fn)
            bfv[fn] = *(const bf16x8*)(Bs + (wc + fn*16 + r)*32 + g*8);
        #pragma unroll
        for (int fm = 0; fm < FM; ++fm)
            #pragma unroll
            for (int fn = 0; fn < FN; ++fn)
                acc[fm][fn] = __builtin_amdgcn_mfma_f32_16x16x32_bf16(
                    af[fm], bfv[fn], acc[fm][fn], 0, 0, 0);
        __syncthreads();
    }
    #pragma unroll
    for (int fm = 0; fm < FM; ++fm)
        #pragma unroll
        for (int fn = 0; fn < FN; ++fn)
            #pragma unroll
            for (int rr = 0; rr < 4; ++rr) {
                int m = m0 + wr + fm*16 + g*4 + rr;
                int n = n0 + wc + fn*16 + r;
                float v = acc[fm][fn][rr] * mult;
                if (MODE == 0) {
                    Cf[(size_t)m*N + n] = v;
                } else {
                    int b = m >> 11, s = m & (NS-1), hh = n >> 6, d = n & (ND-1);
                    Cb[((size_t)(b*NH + hh)*NS + s)*ND + d] = f2bf(v);
                }
            }
}

__global__ __launch_bounds__(256)
void gemm_qkv_kernel(const short* __restrict__ X,
                     const short* __restrict__ Wq, const short* __restrict__ Wk,
                     const short* __restrict__ Wv,
                     short* __restrict__ Q, short* __restrict__ Kd, short* __restrict__ V)
{
    __shared__ short As[128*32], Bs[128*32];
    const short* Bm; short* Dst; float mult;
    if (blockIdx.z == 0)      { Bm = Wq; Dst = Q;  mult = FSCALE * LOG2E; }  // exp2-space
    else if (blockIdx.z == 1) { Bm = Wk; Dst = Kd; mult = 1.f; }
    else                      { Bm = Wv; Dst = V;  mult = 1.f; }
    gemm_body<4,4,1>(X, Bm, nullptr, Dst, NHID, NHID, mult, blockIdx.x, blockIdx.y, As, Bs);
}

__global__ __launch_bounds__(256)
void gemm_out_kernel(const short* __restrict__ A, const short* __restrict__ Wo,
                     float* __restrict__ C)
{
    __shared__ short As[64*32], Bs[128*32];
    gemm_body<2,4,0>(A, Wo, C, nullptr, NHID, NHID, 1.f, blockIdx.x, blockIdx.y, As, Bs);
}

// ---------------- forget gate: LF2[b,h,s] = log2(sigmoid(x@Wf.T+bf)+1e-6) ------
__global__ __launch_bounds__(256)
void fgate_kernel(const float* __restrict__ X, const float* __restrict__ Wf,
                  const float* __restrict__ bf, float* __restrict__ LF) {
    const int lane = threadIdx.x & 63;
    const int m = blockIdx.x * 4 + (threadIdx.x >> 6);
    const int b = m >> 11, s = m & (NS - 1);
    float xv[16];
    #pragma unroll
    for (int w = 0; w < 16; ++w) xv[w] = X[(size_t)m * NHID + w * 64 + lane];
    for (int h = 0; h < NH; ++h) {
        float p = 0.f;
        #pragma unroll
        for (int w = 0; w < 16; ++w)
            p = fmaf(xv[w], Wf[(size_t)h * NHID + w * 64 + lane], p);
        #pragma unroll
        for (int off = 32; off > 0; off >>= 1) p += __shfl_down(p, off);
        if (lane == 0) {
            float z = p + bf[h];
            float f = 1.f / (1.f + expf(-z));
            LF[(size_t)(b * NH + h) * NS + s] = __log2f(f + 1e-6f);   // log2-space
        }
    }
}

// ---------------- inclusive cumsum over S per (b,h) ----------------
__global__ __launch_bounds__(256)
void cumsum_kernel(const float* __restrict__ LF, float* __restrict__ CUM) {
    __shared__ float ps[256];
    const int t = threadIdx.x;
    const float* src = LF + (size_t)blockIdx.x * NS;
    float* dst       = CUM + (size_t)blockIdx.x * NS;
    float v[8];
    float tot = 0.f;
    #pragma unroll
    for (int i = 0; i < 8; ++i) { v[i] = src[t * 8 + i]; tot += v[i]; v[i] = tot; }
    ps[t] = tot;
    __syncthreads();
    for (int off = 1; off < 256; off <<= 1) {
        float add = (t >= off) ? ps[t - off] : 0.f;
        __syncthreads();
        ps[t] += add;
        __syncthreads();
    }
    float excl = ps[t] - tot;
    #pragma unroll
    for (int i = 0; i < 8; ++i) dst[t * 8 + i] = excl + v[i];
}

// ---------------- MFMA flash attention, 8-wave QBLK=128, dbuf KV ----------------
// Swapped QK^T (S^T = K·Q^T) in exp2-space; fold-paired i-tiles for balance.
__global__ __launch_bounds__(512)
void attn_mfma(const short* __restrict__ Qg, const short* __restrict__ Kg,
               const short* __restrict__ Vg, const float* __restrict__ CUM,
               short* __restrict__ ATT) {
    __shared__ short Ks[2][64*64];   // [buf][j][d] row-major, XOR-swizzled
    __shared__ short Vs[2][64*64];   // [buf] subtiled [jb][db][4][16] for tr reads
    __shared__ short Ps[8][16*64];   // per-wave P tile [i][j], XOR-swizzled
    const int t = threadIdx.x, w = t>>6, l = t&63, g = l>>4, r = l&15;
    const int bh = blockIdx.y, b = bh>>4, h = bh&15;
    const int pp = blockIdx.x;       // fold pair id 0..7
    const size_t base = (size_t)bh * NS * ND;
    const float* cumb = CUM + (size_t)bh * NS;
    char* PsB = (char*)Ps[w];

    #pragma unroll 1
    for (int half = 0; half < 2; ++half) {
        const int tile = half ? (NT - 1 - pp) : pp;
        const int i0 = tile * QBLK;
        const int iwm = i0 + w*16;                 // wave's min q-row
        const int iw  = iwm + r;                   // lane's q-row
        bf16x8 qf[2];                               // Q pre-scaled by FSCALE*log2e
        qf[0] = *(const bf16x8*)(Qg + base + (size_t)iw*ND + g*8);
        qf[1] = *(const bf16x8*)(Qg + base + (size_t)iw*ND + 32 + g*8);
        const float cum_i = cumb[iw];
        float mrun = -1e30f, lrun = 0.f;
        f32x4 acc[4] = {};
        const int nj = 2*tile + 2;                 // 64-wide j-units

        // ---- prologue: stage unit 0 into buf 0 ----
        {
            const int ci = w*64 + l;
            int row = ci >> 3, col = (ci & 7) * 8;
            int lcol = col ^ ((row & 7) << 3);
            gload16(Kg + base + (size_t)row*ND + lcol, Ks[0] + w*512);
            int st = ci >> 3, q8 = ci & 7;
            int jb = st >> 2, db = st & 3, jj = q8 >> 1, dh = q8 & 1;
            gload16(Vg + base + (size_t)(jb*4 + jj)*ND + db*16 + dh*8, Vs[0] + w*512);
        }
        __syncthreads();

        #pragma unroll 1
        for (int u = 0; u < nj; ++u) {
            const int cur = u & 1, j0 = u*64;
            // ---- stage next unit into the other buffer (overlapped w/ compute) ----
            if (u + 1 < nj) {
                const int jn = j0 + 64;
                const int ci = w*64 + l;
                int row = ci >> 3, col = (ci & 7) * 8;
                int lcol = col ^ ((row & 7) << 3);
                gload16(Kg + base + (size_t)(jn+row)*ND + lcol, Ks[cur^1] + w*512);
                int st = ci >> 3, q8 = ci & 7;
                int jb = st >> 2, db = st & 3, jj = q8 >> 1, dh = q8 & 1;
                gload16(Vg + base + (size_t)(jn + jb*4 + jj)*ND + db*16 + dh*8,
                        Vs[cur^1] + w*512);
            }

            if (j0 <= iwm + 15) {                  // wave has live rows
                const char* KsB = (const char*)Ks[cur];
                const unsigned vsb = lds_addr(Vs[cur]);
                // ---- S^T = K·Q^T ----
                f32x4 sT[4];
                __builtin_amdgcn_s_setprio(1);
                #pragma unroll
                for (int fj = 0; fj < 4; ++fj) {
                    int row = fj*16 + r;
                    unsigned swz = (unsigned)((row & 7) << 4);
                    bf16x8 k0v = *(const bf16x8*)(KsB + ((row*128 +      g*16) ^ swz));
                    bf16x8 k1v = *(const bf16x8*)(KsB + ((row*128 + 64 + g*16) ^ swz));
                    f32x4 z = {};
                    z = __builtin_amdgcn_mfma_f32_16x16x32_bf16(k0v, qf[0], z, 0, 0, 0);
                    z = __builtin_amdgcn_mfma_f32_16x16x32_bf16(k1v, qf[1], z, 0, 0, 0);
                    sT[fj] = z;
                }
                __builtin_amdgcn_s_setprio(0);

                // ---- bias + mask; lane-local online softmax (exp2-space) ----
                float p[16];
                const bool pd = (j0 + 63 > iwm);   // partially-masked unit for this wave
                #pragma unroll
                for (int fj = 0; fj < 4; ++fj) {
                    f32x4 cj = *(const f32x4*)(cumb + j0 + fj*16 + g*4);
                    #pragma unroll
                    for (int rr = 0; rr < 4; ++rr) {
                        float sv = sT[fj][rr] + cum_i - cj[rr];
                        if (pd && (j0 + fj*16 + g*4 + rr > iw)) sv = -1e30f;
                        p[fj*4+rr] = sv;
                    }
                }
                float mx = p[0];
                #pragma unroll
                for (int q = 1; q < 16; ++q) mx = fmaxf(mx, p[q]);
                mx = fmaxf(mx, __shfl_xor(mx, 16));
                mx = fmaxf(mx, __shfl_xor(mx, 32));
                float newm = fmaxf(mrun, mx);
                float sc = exp2f(mrun - newm);
                mrun = newm;
                float tsum = 0.f;
                #pragma unroll
                for (int q = 0; q < 16; ++q) { p[q] = exp2f(p[q] - newm); tsum += p[q]; }
                tsum += __shfl_xor(tsum, 16);
                tsum += __shfl_xor(tsum, 32);
                lrun = lrun * sc + tsum;

                // ---- P -> per-wave LDS (bf16, swizzled) ----
                {
                    unsigned swz = (unsigned)((r & 7) << 4);
                    #pragma unroll
                    for (int fj = 0; fj < 4; ++fj) {
                        s16x4 pk;
                        pk[0]=f2bf(p[fj*4+0]); pk[1]=f2bf(p[fj*4+1]);
                        pk[2]=f2bf(p[fj*4+2]); pk[3]=f2bf(p[fj*4+3]);
                        *(s16x4*)(PsB + ((r*128 + fj*32 + g*8) ^ swz)) = pk;
                    }
                }

                // ---- rescale O accum ----
                float scr[4];
                #pragma unroll
                for (int rr = 0; rr < 4; ++rr) scr[rr] = __shfl(sc, g*4 + rr);
                #pragma unroll
                for (int fd = 0; fd < 4; ++fd)
                    #pragma unroll
                    for (int rr = 0; rr < 4; ++rr) acc[fd][rr] *= scr[rr];

                // ---- PV: O += P·V ----
                bf16x8 pa[2];
                {
                    unsigned swz = (unsigned)((r & 7) << 4);
                    pa[0] = *(const bf16x8*)(PsB + ((r*128 +      g*16) ^ swz));
                    pa[1] = *(const bf16x8*)(PsB + ((r*128 + 64 + g*16) ^ swz));
                }
                i32x2 vt[4][4];
                #pragma unroll
                for (int fd = 0; fd < 4; ++fd)
                    #pragma unroll
                    for (int jc = 0; jc < 2; ++jc)
                        #pragma unroll
                        for (int hh = 0; hh < 2; ++hh) {
                            unsigned st = (unsigned)((jc*8 + 2*g + hh)*4 + fd);
                            unsigned ad = vsb + st*128 + (unsigned)r*8;
                            asm volatile("ds_read_b64_tr_b16 %0, %1"
                                         : "=v"(vt[fd][jc*2+hh]) : "v"(ad));
                        }
                asm volatile("s_waitcnt lgkmcnt(0)" ::: "memory");
                __builtin_amdgcn_sched_barrier(0);
                __builtin_amdgcn_s_setprio(1);
                #pragma unroll
                for (int fd = 0; fd < 4; ++fd) {
                    union { bf16x8 v; i32x2 d2[2]; } u0, u1;
                    u0.d2[0] = vt[fd][0]; u0.d2[1] = vt[fd][1];
                    u1.d2[0] = vt[fd][2]; u1.d2[1] = vt[fd][3];
                    acc[fd] = __builtin_amdgcn_mfma_f32_16x16x32_bf16(pa[0], u0.v, acc[fd], 0, 0, 0);
                    acc[fd] = __builtin_amdgcn_mfma_f32_16x16x32_bf16(pa[1], u1.v, acc[fd], 0, 0, 0);
                }
                __builtin_amdgcn_s_setprio(0);
            }
            __syncthreads();   // drains vmcnt(0): next-unit stage complete; buffers safe
        }

        // ---- epilogue ----
        float linv[4];
        #pragma unroll
        for (int rr = 0; rr < 4; ++rr) linv[rr] = 1.f / __shfl(lrun, g*4 + rr);
        #pragma unroll
        for (int fd = 0; fd < 4; ++fd)
            #pragma unroll
            for (int rr = 0; rr < 4; ++rr) {
                int i = i0 + w*16 + g*4 + rr;
                ATT[((size_t)(b*NS + i))*NHID + h*ND + fd*16 + r] = f2bf(acc[fd][rr] * linv[rr]);
            }
        __syncthreads();       // before next tile's prologue restages buf 0
    }
}

extern "C" void kernel_launch(void* const* d_in, const int* in_sizes, int n_in,
                              void* d_out, int out_size, void* d_ws, size_t ws_size,
                              hipStream_t stream) {
    const float* x  = (const float*)d_in[0];
    const float* Wq = (const float*)d_in[1];
    const float* Wk = (const float*)d_in[2];
    const float* Wv = (const float*)d_in[3];
    const float* Wf = (const float*)d_in[4];
    const float* bf = (const float*)d_in[5];
    const float* Wo = (const float*)d_in[6];
    float* out = (float*)d_out;

    const size_t NTOK = (size_t)NB * NS;
    short* xb  = (short*)d_ws;
    short* Wqb = xb  + NTOK * NHID;
    short* Wkb = Wqb + (size_t)NHID * NHID;
    short* Wvb = Wkb + (size_t)NHID * NHID;
    short* Wob = Wvb + (size_t)NHID * NHID;
    short* Qb  = Wob + (size_t)NHID * NHID;
    short* Kb  = Qb  + NTOK * NHID;
    short* Vb  = Kb  + NTOK * NHID;
    short* ATTb= Vb  + NTOK * NHID;
    float* LF  = (float*)(ATTb + NTOK * NHID);
    float* CUM = LF + (size_t)NB * NH * NS;

    cast_x_kernel<<<2048, 256, 0, stream>>>(x, xb);
    cast_w_kernel<<<dim3(512, 4), 256, 0, stream>>>(Wq, Wk, Wv, Wo, Wqb, Wkb, Wvb, Wob);
    gemm_qkv_kernel<<<dim3(8, 32, 3), 256, 0, stream>>>(xb, Wqb, Wkb, Wvb, Qb, Kb, Vb);
    fgate_kernel<<<(int)NTOK / 4, 256, 0, stream>>>(x, Wf, bf, LF);
    cumsum_kernel<<<NB * NH, 256, 0, stream>>>(LF, CUM);
    attn_mfma<<<dim3(NT/2, NB * NH), 512, 0, stream>>>(Qb, Kb, Vb, CUM, ATTb);
    gemm_out_kernel<<<dim3(8, 64), 256, 0, stream>>>(ATTb, Wob, out);
}

// Round 5
// 110.477 us; speedup vs baseline: 14.3535x; 1.3783x over previous
//
#include <hip/hip_runtime.h>
#include <hip/hip_bf16.h>
#include <math.h>

typedef __attribute__((ext_vector_type(8))) short bf16x8;
typedef __attribute__((ext_vector_type(4))) short s16x4;
typedef __attribute__((ext_vector_type(4))) float f32x4;
typedef __attribute__((ext_vector_type(2))) int i32x2;

constexpr int NB = 2, NS = 2048, NHID = 1024, NH = 16, ND = 64;
constexpr float FSCALE = 0.125f;                 // D^-0.5
constexpr float LOG2E  = 1.44269504088896f;
constexpr int QBLK = 128, NT = NS / QBLK;        // 16 i-tiles
constexpr float DROP_MARGIN = 30.0f;             // log2 units: dropped mass < S*2^-30

__device__ __forceinline__ short f2bf(float f) {
    union { __hip_bfloat16 h; short s; } u;
    u.h = __float2bfloat16(f);
    return u.s;
}

__device__ __forceinline__ float bf2f(short s) {
    union { unsigned u; float f; } u;
    u.u = ((unsigned)(unsigned short)s) << 16;
    return u.f;
}

__device__ __forceinline__ void gload16(const void* g, void* l) {
    __builtin_amdgcn_global_load_lds(
        (const __attribute__((address_space(1))) unsigned*)g,
        (__attribute__((address_space(3))) unsigned*)l, 16, 0, 0);
}

__device__ __forceinline__ unsigned lds_addr(void* p) {
    return (unsigned)(size_t)(__attribute__((address_space(3))) void*)p;
}

// ---------------- fp32 -> bf16 casts ----------------
__global__ __launch_bounds__(256)
void cast_x_kernel(const float* __restrict__ s, short* __restrict__ d) {
    size_t i = ((size_t)blockIdx.x*256 + threadIdx.x)*8;
    float4 a = *(const float4*)(s+i);
    float4 b = *(const float4*)(s+i+4);
    bf16x8 o;
    o[0]=f2bf(a.x); o[1]=f2bf(a.y); o[2]=f2bf(a.z); o[3]=f2bf(a.w);
    o[4]=f2bf(b.x); o[5]=f2bf(b.y); o[6]=f2bf(b.z); o[7]=f2bf(b.w);
    *(bf16x8*)(d+i) = o;
}

__global__ __launch_bounds__(256)
void cast_w_kernel(const float* __restrict__ s0, const float* __restrict__ s1,
                   const float* __restrict__ s2, const float* __restrict__ s3,
                   short* __restrict__ d0, short* __restrict__ d1,
                   short* __restrict__ d2, short* __restrict__ d3) {
    const float* s; short* d;
    switch (blockIdx.y) {
        case 0:  s = s0; d = d0; break;
        case 1:  s = s1; d = d1; break;
        case 2:  s = s2; d = d2; break;
        default: s = s3; d = d3; break;
    }
    size_t i = ((size_t)blockIdx.x*256 + threadIdx.x)*8;
    float4 a = *(const float4*)(s+i);
    float4 b = *(const float4*)(s+i+4);
    bf16x8 o;
    o[0]=f2bf(a.x); o[1]=f2bf(a.y); o[2]=f2bf(a.z); o[3]=f2bf(a.w);
    o[4]=f2bf(b.x); o[5]=f2bf(b.y); o[6]=f2bf(b.z); o[7]=f2bf(b.w);
    *(bf16x8*)(d+i) = o;
}

// ---------------- bf16 MFMA GEMM: C = A @ W^T ----------------
template<int FM, int FN, int MODE>
__device__ __forceinline__ void gemm_body(
    const short* __restrict__ A, const short* __restrict__ Bm,
    float* __restrict__ Cf, short* __restrict__ Cb,
    int N, int K, float mult, int bx, int by, short* As, short* Bs)
{
    constexpr int BM = FM*32, BN = FN*32;
    const int t = threadIdx.x, w = t>>6, l = t&63, g = l>>4, r = l&15;
    const int m0 = by*BM, n0 = bx*BN;
    const int wr = (w>>1)*(FM*16), wc = (w&1)*(FN*16);
    f32x4 acc[FM][FN] = {};
    for (int k0 = 0; k0 < K; k0 += 32) {
        #pragma unroll
        for (int c = 0; c < (BM*4)/256; ++c) {
            int ci = (c*4 + w)*64 + l;
            gload16(A + (size_t)(m0 + (ci>>2))*K + k0 + (ci&3)*8, As + (c*4+w)*512);
        }
        #pragma unroll
        for (int c = 0; c < (BN*4)/256; ++c) {
            int ci = (c*4 + w)*64 + l;
            gload16(Bm + (size_t)(n0 + (ci>>2))*K + k0 + (ci&3)*8, Bs + (c*4+w)*512);
        }
        __syncthreads();
        bf16x8 af[FM], bfv[FN];
        #pragma unroll
        for (int fm = 0; fm < FM; ++fm)
            af[fm] = *(const bf16x8*)(As + (wr + fm*16 + r)*32 + g*8);
        #pragma unroll
        for (int fn = 0; fn < FN; ++fn)
            bfv[fn] = *(const bf16x8*)(Bs + (wc + fn*16 + r)*32 + g*8);
        #pragma unroll
        for (int fm = 0; fm < FM; ++fm)
            #pragma unroll
            for (int fn = 0; fn < FN; ++fn)
                acc[fm][fn] = __builtin_amdgcn_mfma_f32_16x16x32_bf16(
                    af[fm], bfv[fn], acc[fm][fn], 0, 0, 0);
        __syncthreads();
    }
    #pragma unroll
    for (int fm = 0; fm < FM; ++fm)
        #pragma unroll
        for (int fn = 0; fn < FN; ++fn)
            #pragma unroll
            for (int rr = 0; rr < 4; ++rr) {
                int m = m0 + wr + fm*16 + g*4 + rr;
                int n = n0 + wc + fn*16 + r;
                float v = acc[fm][fn][rr] * mult;
                if (MODE == 0) {
                    Cf[(size_t)m*N + n] = v;
                } else {
                    int b = m >> 11, s = m & (NS-1), hh = n >> 6, d = n & (ND-1);
                    Cb[((size_t)(b*NH + hh)*NS + s)*ND + d] = f2bf(v);
                }
            }
}

__global__ __launch_bounds__(256)
void gemm_qkv_kernel(const short* __restrict__ X,
                     const short* __restrict__ Wq, const short* __restrict__ Wk,
                     const short* __restrict__ Wv,
                     short* __restrict__ Q, short* __restrict__ Kd, short* __restrict__ V)
{
    __shared__ short As[128*32], Bs[128*32];
    const short* Bm; short* Dst; float mult;
    if (blockIdx.z == 0)      { Bm = Wq; Dst = Q;  mult = FSCALE * LOG2E; }  // exp2-space
    else if (blockIdx.z == 1) { Bm = Wk; Dst = Kd; mult = 1.f; }
    else                      { Bm = Wv; Dst = V;  mult = 1.f; }
    gemm_body<4,4,1>(X, Bm, nullptr, Dst, NHID, NHID, mult, blockIdx.x, blockIdx.y, As, Bs);
}

__global__ __launch_bounds__(256)
void gemm_out_kernel(const short* __restrict__ A, const short* __restrict__ Wo,
                     float* __restrict__ C)
{
    __shared__ short As[64*32], Bs[128*32];
    gemm_body<2,4,0>(A, Wo, C, nullptr, NHID, NHID, 1.f, blockIdx.x, blockIdx.y, As, Bs);
}

// ---------------- forget gate: LF2[b,h,s] = log2(sigmoid(x@Wf.T+bf)+1e-6) ------
__global__ __launch_bounds__(256)
void fgate_kernel(const float* __restrict__ X, const float* __restrict__ Wf,
                  const float* __restrict__ bf, float* __restrict__ LF) {
    const int lane = threadIdx.x & 63;
    const int m = blockIdx.x * 4 + (threadIdx.x >> 6);
    const int b = m >> 11, s = m & (NS - 1);
    float xv[16];
    #pragma unroll
    for (int w = 0; w < 16; ++w) xv[w] = X[(size_t)m * NHID + w * 64 + lane];
    for (int h = 0; h < NH; ++h) {
        float p = 0.f;
        #pragma unroll
        for (int w = 0; w < 16; ++w)
            p = fmaf(xv[w], Wf[(size_t)h * NHID + w * 64 + lane], p);
        #pragma unroll
        for (int off = 32; off > 0; off >>= 1) p += __shfl_down(p, off);
        if (lane == 0) {
            float z = p + bf[h];
            float f = 1.f / (1.f + expf(-z));
            LF[(size_t)(b * NH + h) * NS + s] = __log2f(f + 1e-6f);   // log2-space
        }
    }
}

// ---------------- inclusive cumsum over S per (b,h) ----------------
__global__ __launch_bounds__(256)
void cumsum_kernel(const float* __restrict__ LF, float* __restrict__ CUM) {
    __shared__ float ps[256];
    const int t = threadIdx.x;
    const float* src = LF + (size_t)blockIdx.x * NS;
    float* dst       = CUM + (size_t)blockIdx.x * NS;
    float v[8];
    float tot = 0.f;
    #pragma unroll
    for (int i = 0; i < 8; ++i) { v[i] = src[t * 8 + i]; tot += v[i]; v[i] = tot; }
    ps[t] = tot;
    __syncthreads();
    for (int off = 1; off < 256; off <<= 1) {
        float add = (t >= off) ? ps[t - off] : 0.f;
        __syncthreads();
        ps[t] += add;
        __syncthreads();
    }
    float excl = ps[t] - tot;
    #pragma unroll
    for (int i = 0; i < 8; ++i) dst[t * 8 + i] = excl + v[i];
}

// ---------------- per-(b,h) max K-row norm (for the decay-prune bound) --------
__global__ __launch_bounds__(256)
void knorm_kernel(const short* __restrict__ Kg, float* __restrict__ KNMAX) {
    const int bh = blockIdx.x, t = threadIdx.x;
    const short* Kb = Kg + (size_t)bh * NS * ND;
    float mx = 0.f;
    for (int rr = 0; rr < NS/256; ++rr) {
        int row = t * (NS/256) + rr;
        float s = 0.f;
        const bf16x8* p = (const bf16x8*)(Kb + (size_t)row * ND);
        #pragma unroll
        for (int c = 0; c < 8; ++c) {
            bf16x8 v = p[c];
            #pragma unroll
            for (int e = 0; e < 8; ++e) { float f = bf2f(v[e]); s = fmaf(f, f, s); }
        }
        mx = fmaxf(mx, s);
    }
    __shared__ float red[256];
    red[t] = mx; __syncthreads();
    for (int o = 128; o > 0; o >>= 1) {
        if (t < o) red[t] = fmaxf(red[t], red[t+o]);
        __syncthreads();
    }
    if (t == 0) KNMAX[bh] = sqrtf(red[0]);
}

// ---------------- MFMA flash attention, reverse-j with decay pruning ----------
// Swapped QK^T (S^T = K·Q^T), exp2-space, scores shifted by -cum_i (softmax-
// invariant). Iterate j-units from the diagonal DOWN; block exits when
// Cauchy-Schwarz bound proves all remaining mass < 2^-30 of the running max.
__global__ __launch_bounds__(512)
void attn_mfma(const short* __restrict__ Qg, const short* __restrict__ Kg,
               const short* __restrict__ Vg, const float* __restrict__ CUM,
               const float* __restrict__ KNMAX, short* __restrict__ ATT) {
    __shared__ short Ks[2][64*64];   // [buf][j][d] row-major, XOR-swizzled
    __shared__ short Vs[2][64*64];   // [buf] subtiled [jb][db][4][16] for tr reads
    __shared__ short Ps[8][16*64];   // per-wave P tile [i][j], XOR-swizzled
    const int t = threadIdx.x, w = t>>6, l = t&63, g = l>>4, r = l&15;
    const int bh = blockIdx.y, b = bh>>4, h = bh&15;
    const int tile = blockIdx.x;
    const int i0 = tile * QBLK;
    const size_t base = (size_t)bh * NS * ND;
    const float* cumb = CUM + (size_t)bh * NS;
    char* PsB = (char*)Ps[w];
    const int iwm = i0 + w*16;                  // wave's min q-row
    const int iw  = iwm + r;                    // lane's q-row

    bf16x8 qf[2];                               // Q pre-scaled by FSCALE*log2e
    qf[0] = *(const bf16x8*)(Qg + base + (size_t)iw*ND + g*8);
    qf[1] = *(const bf16x8*)(Qg + base + (size_t)iw*ND + 32 + g*8);
    // ||q_i|| (scaled): row spread over the 4 lanes {r, r+16, r+32, r+48}
    float qs = 0.f;
    #pragma unroll
    for (int e = 0; e < 8; ++e) {
        float f0 = bf2f(qf[0][e]); qs = fmaf(f0, f0, qs);
        float f1 = bf2f(qf[1][e]); qs = fmaf(f1, f1, qs);
    }
    qs += __shfl_xor(qs, 16);
    qs += __shfl_xor(qs, 32);
    const float qkb = sqrtf(qs) * KNMAX[bh];    // bound on |q_s . k| in log2 units

    float mrun = -1e30f, lrun = 0.f;
    f32x4 acc[4] = {};
    const int utop = 2*tile + 1;                // top 64-wide j-unit

    auto STAGE = [&](int jbase, int bufi) {
        const int ci = w*64 + l;
        int row = ci >> 3, col = (ci & 7) * 8;
        int lcol = col ^ ((row & 7) << 3);      // pre-swizzle global source
        gload16(Kg + base + (size_t)(jbase+row)*ND + lcol, Ks[bufi] + w*512);
        int st = ci >> 3, q8 = ci & 7;
        int jb = st >> 2, db = st & 3, jj = q8 >> 1, dh = q8 & 1;
        gload16(Vg + base + (size_t)(jbase + jb*4 + jj)*ND + db*16 + dh*8,
                Vs[bufi] + w*512);
    };

    STAGE(utop*64, 0);
    __syncthreads();

    #pragma unroll 1
    for (int u = utop; u >= 0; --u) {
        const int cur = (utop - u) & 1;
        const int j0 = u * 64;
        if (u > 0) STAGE((u-1)*64, cur^1);      // prefetch next (lower) unit

        const bool live = (j0 <= iwm + 15);
        if (live) {
            const char* KsB = (const char*)Ks[cur];
            const unsigned vsb = lds_addr(Vs[cur]);
            // ---- S^T = K·Q^T ----
            f32x4 sT[4];
            __builtin_amdgcn_s_setprio(1);
            #pragma unroll
            for (int fj = 0; fj < 4; ++fj) {
                int row = fj*16 + r;
                unsigned swz = (unsigned)((row & 7) << 4);
                bf16x8 k0v = *(const bf16x8*)(KsB + ((row*128 +      g*16) ^ swz));
                bf16x8 k1v = *(const bf16x8*)(KsB + ((row*128 + 64 + g*16) ^ swz));
                f32x4 z = {};
                z = __builtin_amdgcn_mfma_f32_16x16x32_bf16(k0v, qf[0], z, 0, 0, 0);
                z = __builtin_amdgcn_mfma_f32_16x16x32_bf16(k1v, qf[1], z, 0, 0, 0);
                sT[fj] = z;
            }
            __builtin_amdgcn_s_setprio(0);

            // ---- relative scores p = qk - cum_j (cum_i dropped: shift-invariant)
            float p[16];
            const bool pd = (j0 + 63 > iwm);
            #pragma unroll
            for (int fj = 0; fj < 4; ++fj) {
                f32x4 cj = *(const f32x4*)(cumb + j0 + fj*16 + g*4);
                #pragma unroll
                for (int rr = 0; rr < 4; ++rr) {
                    float sv = sT[fj][rr] - cj[rr];
                    if (pd && (j0 + fj*16 + g*4 + rr > iw)) sv = -1e30f;
                    p[fj*4+rr] = sv;
                }
            }
            // tree max
            float m0 = fmaxf(fmaxf(fmaxf(p[0],p[1]), fmaxf(p[2],p[3])),
                             fmaxf(fmaxf(p[4],p[5]), fmaxf(p[6],p[7])));
            float m1 = fmaxf(fmaxf(fmaxf(p[8],p[9]), fmaxf(p[10],p[11])),
                             fmaxf(fmaxf(p[12],p[13]), fmaxf(p[14],p[15])));
            float mx = fmaxf(m0, m1);
            mx = fmaxf(mx, __shfl_xor(mx, 16));
            mx = fmaxf(mx, __shfl_xor(mx, 32));
            float newm = fmaxf(mrun, mx);
            float sc = exp2f(mrun - newm);
            mrun = newm;
            float tsum = 0.f;
            #pragma unroll
            for (int q = 0; q < 16; ++q) { p[q] = exp2f(p[q] - newm); tsum += p[q]; }
            tsum += __shfl_xor(tsum, 16);
            tsum += __shfl_xor(tsum, 32);
            lrun = lrun * sc + tsum;

            // ---- P -> per-wave LDS (bf16, swizzled) ----
            {
                unsigned swz = (unsigned)((r & 7) << 4);
                #pragma unroll
                for (int fj = 0; fj < 4; ++fj) {
                    s16x4 pk;
                    pk[0]=f2bf(p[fj*4+0]); pk[1]=f2bf(p[fj*4+1]);
                    pk[2]=f2bf(p[fj*4+2]); pk[3]=f2bf(p[fj*4+3]);
                    *(s16x4*)(PsB + ((r*128 + fj*32 + g*8) ^ swz)) = pk;
                }
            }

            // ---- rescale O accum ----
            float scr[4];
            #pragma unroll
            for (int rr = 0; rr < 4; ++rr) scr[rr] = __shfl(sc, g*4 + rr);
            #pragma unroll
            for (int fd = 0; fd < 4; ++fd)
                #pragma unroll
                for (int rr = 0; rr < 4; ++rr) acc[fd][rr] *= scr[rr];

            // ---- PV: O += P·V ----
            bf16x8 pa[2];
            {
                unsigned swz = (unsigned)((r & 7) << 4);
                pa[0] = *(const bf16x8*)(PsB + ((r*128 +      g*16) ^ swz));
                pa[1] = *(const bf16x8*)(PsB + ((r*128 + 64 + g*16) ^ swz));
            }
            i32x2 vt[4][4];
            #pragma unroll
            for (int fd = 0; fd < 4; ++fd)
                #pragma unroll
                for (int jc = 0; jc < 2; ++jc)
                    #pragma unroll
                    for (int hh = 0; hh < 2; ++hh) {
                        unsigned st = (unsigned)((jc*8 + 2*g + hh)*4 + fd);
                        unsigned ad = vsb + st*128 + (unsigned)r*8;
                        asm volatile("ds_read_b64_tr_b16 %0, %1"
                                     : "=v"(vt[fd][jc*2+hh]) : "v"(ad));
                    }
            asm volatile("s_waitcnt lgkmcnt(0)" ::: "memory");
            __builtin_amdgcn_sched_barrier(0);
            __builtin_amdgcn_s_setprio(1);
            #pragma unroll
            for (int fd = 0; fd < 4; ++fd) {
                union { bf16x8 v; i32x2 d2[2]; } u0, u1;
                u0.d2[0] = vt[fd][0]; u0.d2[1] = vt[fd][1];
                u1.d2[0] = vt[fd][2]; u1.d2[1] = vt[fd][3];
                acc[fd] = __builtin_amdgcn_mfma_f32_16x16x32_bf16(pa[0], u0.v, acc[fd], 0, 0, 0);
                acc[fd] = __builtin_amdgcn_mfma_f32_16x16x32_bf16(pa[1], u1.v, acc[fd], 0, 0, 0);
            }
            __builtin_amdgcn_s_setprio(0);
        }

        if (u > 0) {
            // decay pruning: remaining j < j0 all have score <= qkb - cum[j0-1]
            // (cum monotone non-increasing). Done once that's 30 log2 below max.
            bool d = live ? (qkb - cumb[j0-1] < mrun - DROP_MARGIN) : false;
            asm volatile("s_waitcnt vmcnt(0)" ::: "memory");  // staging landed
            if (__syncthreads_and((int)d)) break;
        }
    }

    // ---- epilogue ----
    float linv[4];
    #pragma unroll
    for (int rr = 0; rr < 4; ++rr) linv[rr] = 1.f / __shfl(lrun, g*4 + rr);
    #pragma unroll
    for (int fd = 0; fd < 4; ++fd)
        #pragma unroll
        for (int rr = 0; rr < 4; ++rr) {
            int i = i0 + w*16 + g*4 + rr;
            ATT[((size_t)(b*NS + i))*NHID + h*ND + fd*16 + r] = f2bf(acc[fd][rr] * linv[rr]);
        }
}

extern "C" void kernel_launch(void* const* d_in, const int* in_sizes, int n_in,
                              void* d_out, int out_size, void* d_ws, size_t ws_size,
                              hipStream_t stream) {
    const float* x  = (const float*)d_in[0];
    const float* Wq = (const float*)d_in[1];
    const float* Wk = (const float*)d_in[2];
    const float* Wv = (const float*)d_in[3];
    const float* Wf = (const float*)d_in[4];
    const float* bf = (const float*)d_in[5];
    const float* Wo = (const float*)d_in[6];
    float* out = (float*)d_out;

    const size_t NTOK = (size_t)NB * NS;
    short* xb  = (short*)d_ws;
    short* Wqb = xb  + NTOK * NHID;
    short* Wkb = Wqb + (size_t)NHID * NHID;
    short* Wvb = Wkb + (size_t)NHID * NHID;
    short* Wob = Wvb + (size_t)NHID * NHID;
    short* Qb  = Wob + (size_t)NHID * NHID;
    short* Kb  = Qb  + NTOK * NHID;
    short* Vb  = Kb  + NTOK * NHID;
    short* ATTb= Vb  + NTOK * NHID;
    float* LF  = (float*)(ATTb + NTOK * NHID);
    float* CUM = LF + (size_t)NB * NH * NS;
    float* KNM = CUM + (size_t)NB * NH * NS;

    cast_x_kernel<<<2048, 256, 0, stream>>>(x, xb);
    cast_w_kernel<<<dim3(512, 4), 256, 0, stream>>>(Wq, Wk, Wv, Wo, Wqb, Wkb, Wvb, Wob);
    gemm_qkv_kernel<<<dim3(8, 32, 3), 256, 0, stream>>>(xb, Wqb, Wkb, Wvb, Qb, Kb, Vb);
    fgate_kernel<<<(int)NTOK / 4, 256, 0, stream>>>(x, Wf, bf, LF);
    cumsum_kernel<<<NB * NH, 256, 0, stream>>>(LF, CUM);
    knorm_kernel<<<NB * NH, 256, 0, stream>>>(Kb, KNM);
    attn_mfma<<<dim3(NT, NB * NH), 512, 0, stream>>>(Qb, Kb, Vb, CUM, KNM, ATTb);
    gemm_out_kernel<<<dim3(8, 64), 256, 0, stream>>>(ATTb, Wob, out);
}